// Round 1
// baseline (3021.829 us; speedup 1.0000x reference)
//
#include <hip/hip_runtime.h>

#define HEADS 4
#define HD 32
#define CH 128   // IN_CH == HEADS*HD == 128

// ---------------- Kernel A: xt = x @ W, plus a_src/a_dst dots ----------------
// 256 threads/block, 32 rows/block: each thread owns 4 rows x 4 cols.
__global__ __launch_bounds__(256) void k_gemm(
    const float* __restrict__ x, const float* __restrict__ W,
    const float* __restrict__ att_src, const float* __restrict__ att_dst,
    float* __restrict__ xt, float* __restrict__ a_src, float* __restrict__ a_dst,
    int N)
{
    __shared__ float Wl[CH * CH];     // 64 KB
    __shared__ float xl[32][CH];      // 16 KB
    const int tid = threadIdx.x;

    // stage W into LDS (vectorized, coalesced)
    {
        const float4* W4 = (const float4*)W;
        float4* Wl4 = (float4*)Wl;
        #pragma unroll
        for (int i = 0; i < (CH * CH / 4) / 256; ++i)   // 16 iters
            Wl4[tid + i * 256] = W4[tid + i * 256];
    }

    const int c32 = tid & 31;   // col-quad index: cols [c32*4, c32*4+3]
    const int rg  = tid >> 5;   // row group 0..7 -> rows rg*4..rg*4+3
    const int col = c32 * 4;
    const int h   = c32 >> 3;   // head of this col quad
    const float4 atS = ((const float4*)att_src)[c32];
    const float4 atD = ((const float4*)att_dst)[c32];

    const int r0 = blockIdx.x * 32;
    // stage 32 x-rows into LDS
    {
        const float4* x4 = (const float4*)x;
        float4* xl4 = (float4*)xl;
        #pragma unroll
        for (int i = 0; i < 4; ++i) {
            int f  = tid + i * 256;        // 0..1023
            int rl = f >> 5, c4 = f & 31;
            int r  = r0 + rl;
            float4 v = make_float4(0.f, 0.f, 0.f, 0.f);
            if (r < N) v = x4[(size_t)r * 32 + c4];
            xl4[rl * 32 + c4] = v;
        }
    }
    __syncthreads();

    float4 acc[4];
    #pragma unroll
    for (int i = 0; i < 4; ++i) acc[i] = make_float4(0.f, 0.f, 0.f, 0.f);

    const int rbase = rg * 4;
    for (int k = 0; k < CH; k += 4) {
        float4 w0 = *(const float4*)&Wl[(k + 0) * CH + col];
        float4 w1 = *(const float4*)&Wl[(k + 1) * CH + col];
        float4 w2 = *(const float4*)&Wl[(k + 2) * CH + col];
        float4 w3 = *(const float4*)&Wl[(k + 3) * CH + col];
        #pragma unroll
        for (int rr = 0; rr < 4; ++rr) {
            float4 xv = *(const float4*)&xl[rbase + rr][k];
            acc[rr].x += xv.x * w0.x + xv.y * w1.x + xv.z * w2.x + xv.w * w3.x;
            acc[rr].y += xv.x * w0.y + xv.y * w1.y + xv.z * w2.y + xv.w * w3.y;
            acc[rr].z += xv.x * w0.z + xv.y * w1.z + xv.z * w2.z + xv.w * w3.z;
            acc[rr].w += xv.x * w0.w + xv.y * w1.w + xv.z * w2.w + xv.w * w3.w;
        }
    }

    #pragma unroll
    for (int rr = 0; rr < 4; ++rr) {
        int r = r0 + rbase + rr;          // uniform across the 32-lane group
        if (r < N) {
            ((float4*)xt)[(size_t)r * 32 + c32] = acc[rr];
            float ps = acc[rr].x * atS.x + acc[rr].y * atS.y + acc[rr].z * atS.z + acc[rr].w * atS.w;
            float pd = acc[rr].x * atD.x + acc[rr].y * atD.y + acc[rr].z * atD.z + acc[rr].w * atD.w;
            #pragma unroll
            for (int m = 1; m < 8; m <<= 1) {   // reduce 8 col-quads of one head
                ps += __shfl_xor(ps, m, 64);
                pd += __shfl_xor(pd, m, 64);
            }
            if ((c32 & 7) == 0) {
                a_src[(size_t)r * 4 + h] = ps;
                a_dst[(size_t)r * 4 + h] = pd;
            }
        }
    }
}

// ---------------- Kernel B: edge scatter-aggregate (atomics) ----------------
// one 32-lane group per edge; lane l handles cols [4l, 4l+3], head l>>3.
__global__ __launch_bounds__(256) void k_edge(
    const int* __restrict__ ei, int E, int N,
    const float* __restrict__ a_src, const float* __restrict__ a_dst,
    const float* __restrict__ xt,
    float* __restrict__ segsum, float* __restrict__ out)
{
    int g = blockIdx.x * 8 + (threadIdx.x >> 5);
    int l = threadIdx.x & 31;
    int total = E + N;
    if (g >= total) return;

    int src, dst;
    if (g < E) { src = ei[g]; dst = ei[E + g]; }
    else       { src = g - E; dst = src; }     // self-loop

    int h = l >> 3;
    float logit = a_src[(size_t)src * 4 + h] + a_dst[(size_t)dst * 4 + h];
    logit = (logit >= 0.f) ? logit : 0.2f * logit;   // LeakyReLU(0.2)
    float w = __expf(logit);                          // no max-subtract: ratio identical

    if ((l & 7) == 0) unsafeAtomicAdd(&segsum[(size_t)dst * 4 + h], w);

    float4 xv = ((const float4*)xt)[(size_t)src * 32 + l];
    float* op = out + (size_t)dst * 128 + l * 4;
    unsafeAtomicAdd(op + 0, w * xv.x);
    unsafeAtomicAdd(op + 1, w * xv.y);
    unsafeAtomicAdd(op + 2, w * xv.z);
    unsafeAtomicAdd(op + 3, w * xv.w);
}

// ---------------- Kernel C: normalize + bias + relu, in place ----------------
__global__ __launch_bounds__(256) void k_final(
    float* __restrict__ out, const float* __restrict__ segsum,
    const float* __restrict__ bias, int N)
{
    int i = blockIdx.x * 256 + threadIdx.x;   // one float4 per thread
    if (i >= N * 32) return;
    int n = i >> 5, q = i & 31, h = q >> 3;
    float inv = 1.0f / segsum[(size_t)n * 4 + h];   // >0 always (self-loop)
    float4 v = ((float4*)out)[i];
    float4 b = ((const float4*)bias)[q];
    v.x = fmaxf(fmaf(v.x, inv, b.x), 0.0f);
    v.y = fmaxf(fmaf(v.y, inv, b.y), 0.0f);
    v.z = fmaxf(fmaf(v.z, inv, b.z), 0.0f);
    v.w = fmaxf(fmaf(v.w, inv, b.w), 0.0f);
    ((float4*)out)[i] = v;
}

extern "C" void kernel_launch(void* const* d_in, const int* in_sizes, int n_in,
                              void* d_out, int out_size, void* d_ws, size_t ws_size,
                              hipStream_t stream) {
    const float* x       = (const float*)d_in[0];
    const int*   ei      = (const int*)d_in[1];
    // d_in[2] = batch (unused by reference path)
    const float* W       = (const float*)d_in[3];
    const float* att_src = (const float*)d_in[4];
    const float* att_dst = (const float*)d_in[5];
    const float* bias    = (const float*)d_in[6];

    const int N = in_sizes[0] / CH;
    const int E = in_sizes[1] / 2;
    float* out = (float*)d_out;

    char* ws = (char*)d_ws;
    float* xt     = (float*)ws;                                  // N*128 f32
    float* a_src  = (float*)(ws + (size_t)N * CH * 4);           // N*4
    float* a_dst  = a_src + (size_t)N * 4;                       // N*4
    float* segsum = a_dst + (size_t)N * 4;                       // N*4

    hipMemsetAsync(out,    0, (size_t)N * CH * 4, stream);
    hipMemsetAsync(segsum, 0, (size_t)N * 4 * 4, stream);

    k_gemm<<<(N + 31) / 32, 256, 0, stream>>>(x, W, att_src, att_dst,
                                              xt, a_src, a_dst, N);

    int total = E + N;
    k_edge<<<(total + 7) / 8, 256, 0, stream>>>(ei, E, N, a_src, a_dst,
                                                xt, segsum, out);

    k_final<<<(N * 32 + 255) / 256, 256, 0, stream>>>(out, segsum, bias, N);
}

// Round 2
// 419.143 us; speedup vs baseline: 7.2095x; 7.2095x over previous
//
#include <hip/hip_runtime.h>

#define HEADS 4
#define HD 32
#define CH 128   // IN_CH == HEADS*HD == 128

// ---------------- Kernel A: xt = x @ W, plus a_src/a_dst dots ----------------
__global__ __launch_bounds__(256) void k_gemm(
    const float* __restrict__ x, const float* __restrict__ W,
    const float* __restrict__ att_src, const float* __restrict__ att_dst,
    float* __restrict__ xt, float* __restrict__ a_src, float* __restrict__ a_dst,
    int N)
{
    __shared__ float Wl[CH * CH];     // 64 KB
    __shared__ float xl[32][CH];      // 16 KB
    const int tid = threadIdx.x;

    {
        const float4* W4 = (const float4*)W;
        float4* Wl4 = (float4*)Wl;
        #pragma unroll
        for (int i = 0; i < (CH * CH / 4) / 256; ++i)
            Wl4[tid + i * 256] = W4[tid + i * 256];
    }

    const int c32 = tid & 31;
    const int rg  = tid >> 5;
    const int col = c32 * 4;
    const int h   = c32 >> 3;
    const float4 atS = ((const float4*)att_src)[c32];
    const float4 atD = ((const float4*)att_dst)[c32];

    const int r0 = blockIdx.x * 32;
    {
        const float4* x4 = (const float4*)x;
        float4* xl4 = (float4*)xl;
        #pragma unroll
        for (int i = 0; i < 4; ++i) {
            int f  = tid + i * 256;
            int rl = f >> 5, c4 = f & 31;
            int r  = r0 + rl;
            float4 v = make_float4(0.f, 0.f, 0.f, 0.f);
            if (r < N) v = x4[(size_t)r * 32 + c4];
            xl4[rl * 32 + c4] = v;
        }
    }
    __syncthreads();

    float4 acc[4];
    #pragma unroll
    for (int i = 0; i < 4; ++i) acc[i] = make_float4(0.f, 0.f, 0.f, 0.f);

    const int rbase = rg * 4;
    for (int k = 0; k < CH; k += 4) {
        float4 w0 = *(const float4*)&Wl[(k + 0) * CH + col];
        float4 w1 = *(const float4*)&Wl[(k + 1) * CH + col];
        float4 w2 = *(const float4*)&Wl[(k + 2) * CH + col];
        float4 w3 = *(const float4*)&Wl[(k + 3) * CH + col];
        #pragma unroll
        for (int rr = 0; rr < 4; ++rr) {
            float4 xv = *(const float4*)&xl[rbase + rr][k];
            acc[rr].x += xv.x * w0.x + xv.y * w1.x + xv.z * w2.x + xv.w * w3.x;
            acc[rr].y += xv.x * w0.y + xv.y * w1.y + xv.z * w2.y + xv.w * w3.y;
            acc[rr].z += xv.x * w0.z + xv.y * w1.z + xv.z * w2.z + xv.w * w3.z;
            acc[rr].w += xv.x * w0.w + xv.y * w1.w + xv.z * w2.w + xv.w * w3.w;
        }
    }

    #pragma unroll
    for (int rr = 0; rr < 4; ++rr) {
        int r = r0 + rbase + rr;
        if (r < N) {
            ((float4*)xt)[(size_t)r * 32 + c32] = acc[rr];
            float ps = acc[rr].x * atS.x + acc[rr].y * atS.y + acc[rr].z * atS.z + acc[rr].w * atS.w;
            float pd = acc[rr].x * atD.x + acc[rr].y * atD.y + acc[rr].z * atD.z + acc[rr].w * atD.w;
            #pragma unroll
            for (int m = 1; m < 8; m <<= 1) {
                ps += __shfl_xor(ps, m, 64);
                pd += __shfl_xor(pd, m, 64);
            }
            if ((c32 & 7) == 0) {
                a_src[(size_t)r * 4 + h] = ps;
                a_dst[(size_t)r * 4 + h] = pd;
            }
        }
    }
}

// ---------------- CSR construction ----------------
// deg counts real in-edges only; self-loop contributes the implicit +1 in scan.
__global__ __launch_bounds__(256) void k_count(
    const int* __restrict__ ei, int E, int* __restrict__ deg)
{
    int i = blockIdx.x * 256 + threadIdx.x;
    if (i < E) atomicAdd(&deg[ei[E + i]], 1);
}

// per-block exclusive scan of (deg[i]+1), 1024 elems/block of 256 threads
__global__ __launch_bounds__(256) void k_scan_block(
    const int* __restrict__ deg, int* __restrict__ off, int* __restrict__ bsum, int N)
{
    __shared__ int sdata[256];
    int base = blockIdx.x * 1024;
    int t = threadIdx.x;
    int v[4]; int s = 0;
    #pragma unroll
    for (int j = 0; j < 4; ++j) {
        int i = base + t * 4 + j;
        v[j] = (i < N) ? (deg[i] + 1) : 0;
        s += v[j];
    }
    sdata[t] = s; __syncthreads();
    for (int d = 1; d < 256; d <<= 1) {
        int x = (t >= d) ? sdata[t - d] : 0;
        __syncthreads();
        sdata[t] += x;
        __syncthreads();
    }
    int run = (t > 0) ? sdata[t - 1] : 0;
    if (t == 255) bsum[blockIdx.x] = sdata[255];
    #pragma unroll
    for (int j = 0; j < 4; ++j) {
        int i = base + t * 4 + j;
        if (i < N) off[i] = run;
        run += v[j];
    }
}

// exclusive scan of block sums (nb <= 256), in place
__global__ __launch_bounds__(256) void k_scan_bsum(int* __restrict__ bsum, int nb)
{
    __shared__ int sdata[256];
    int t = threadIdx.x;
    sdata[t] = (t < nb) ? bsum[t] : 0;
    __syncthreads();
    for (int d = 1; d < 256; d <<= 1) {
        int x = (t >= d) ? sdata[t - d] : 0;
        __syncthreads();
        sdata[t] += x;
        __syncthreads();
    }
    if (t < nb) bsum[t] = (t > 0) ? sdata[t - 1] : 0;
}

// add block offsets; init cursor past the self-loop slot; place self-loop
__global__ __launch_bounds__(256) void k_fixup(
    int* __restrict__ off, const int* __restrict__ bsum,
    int* __restrict__ cursor, int* __restrict__ csr, int N, int total)
{
    int i = blockIdx.x * 256 + threadIdx.x;
    if (i > N) return;
    if (i == N) { off[N] = total; return; }
    int o = off[i] + bsum[i >> 10];
    off[i] = o;
    cursor[i] = o + 1;   // slot o holds the self-loop
    csr[o] = i;
}

__global__ __launch_bounds__(256) void k_scatter(
    const int* __restrict__ ei, int E,
    int* __restrict__ cursor, int* __restrict__ csr)
{
    int i = blockIdx.x * 256 + threadIdx.x;
    if (i >= E) return;
    int src = ei[i], dst = ei[E + i];
    int pos = atomicAdd(&cursor[dst], 1);
    csr[pos] = src;
}

// ---------------- Kernel B: per-destination gather + normalize + relu ----------------
// one 64-lane wave per node; half-waves process alternate edges; lane quad q.
__global__ __launch_bounds__(256) void k_gather(
    const int* __restrict__ off, const int* __restrict__ csr,
    const float* __restrict__ a_src, const float* __restrict__ a_dst,
    const float* __restrict__ xt, const float* __restrict__ bias,
    float* __restrict__ out, int N)
{
    int n = blockIdx.x * 4 + (threadIdx.x >> 6);
    if (n >= N) return;
    int l    = threadIdx.x & 63;
    int half = l >> 5;
    int q    = l & 31;
    int h    = q >> 3;

    float ad = a_dst[(size_t)n * 4 + h];
    int s = off[n], e = off[n + 1];

    float4 acc = make_float4(0.f, 0.f, 0.f, 0.f);
    float wsum = 0.f;
    for (int k = s + half; k < e; k += 2) {
        int src = csr[k];
        float as = a_src[(size_t)src * 4 + h];
        float lg = as + ad;
        lg = (lg >= 0.f) ? lg : 0.2f * lg;       // LeakyReLU(0.2)
        float w = __expf(lg);                     // unnormalized; ratio identical
        wsum += w;
        float4 xv = ((const float4*)xt)[(size_t)src * 32 + q];
        acc.x += w * xv.x; acc.y += w * xv.y;
        acc.z += w * xv.z; acc.w += w * xv.w;
    }
    acc.x += __shfl_xor(acc.x, 32, 64);
    acc.y += __shfl_xor(acc.y, 32, 64);
    acc.z += __shfl_xor(acc.z, 32, 64);
    acc.w += __shfl_xor(acc.w, 32, 64);
    wsum  += __shfl_xor(wsum, 32, 64);

    float inv = 1.0f / wsum;                      // >0 (self-loop guarantees an edge)
    float4 b = ((const float4*)bias)[q];
    float4 v;
    v.x = fmaxf(fmaf(acc.x, inv, b.x), 0.0f);
    v.y = fmaxf(fmaf(acc.y, inv, b.y), 0.0f);
    v.z = fmaxf(fmaf(acc.z, inv, b.z), 0.0f);
    v.w = fmaxf(fmaf(acc.w, inv, b.w), 0.0f);
    ((float4*)out)[(size_t)n * 32 + q] = v;
}

extern "C" void kernel_launch(void* const* d_in, const int* in_sizes, int n_in,
                              void* d_out, int out_size, void* d_ws, size_t ws_size,
                              hipStream_t stream) {
    const float* x       = (const float*)d_in[0];
    const int*   ei      = (const int*)d_in[1];
    const float* W       = (const float*)d_in[3];
    const float* att_src = (const float*)d_in[4];
    const float* att_dst = (const float*)d_in[5];
    const float* bias    = (const float*)d_in[6];

    const int N = in_sizes[0] / CH;
    const int E = in_sizes[1] / 2;
    const int total = E + N;
    float* out = (float*)d_out;

    char* ws = (char*)d_ws;
    size_t p = 0;
    float* xt     = (float*)(ws + p); p += (size_t)N * CH * 4;
    float* a_src  = (float*)(ws + p); p += (size_t)N * 4 * 4;
    float* a_dst  = (float*)(ws + p); p += (size_t)N * 4 * 4;
    int*   deg    = (int*)(ws + p);   p += (size_t)N * 4;
    int*   off    = (int*)(ws + p);   p += (size_t)(N + 1) * 4;
    int*   cursor = (int*)(ws + p);   p += (size_t)N * 4;
    int*   bsum   = (int*)(ws + p);   p += 256 * 4;
    int*   csr    = (int*)(ws + p);   p += (size_t)total * 4;

    hipMemsetAsync(deg, 0, (size_t)N * 4, stream);

    k_gemm<<<(N + 31) / 32, 256, 0, stream>>>(x, W, att_src, att_dst,
                                              xt, a_src, a_dst, N);

    k_count<<<(E + 255) / 256, 256, 0, stream>>>(ei, E, deg);

    int nb = (N + 1023) / 1024;
    k_scan_block<<<nb, 256, 0, stream>>>(deg, off, bsum, N);
    k_scan_bsum<<<1, 256, 0, stream>>>(bsum, nb);
    k_fixup<<<(N + 256) / 256, 256, 0, stream>>>(off, bsum, cursor, csr, N, total);
    k_scatter<<<(E + 255) / 256, 256, 0, stream>>>(ei, E, cursor, csr);

    k_gather<<<(N + 3) / 4, 256, 0, stream>>>(off, csr, a_src, a_dst,
                                              xt, bias, out, N);
}

// Round 3
// 314.263 us; speedup vs baseline: 9.6156x; 1.3337x over previous
//
#include <hip/hip_runtime.h>
#include <hip/hip_bf16.h>

#define HEADS 4
#define HD 32
#define CH 128   // IN_CH == HEADS*HD == 128

static __device__ __forceinline__ unsigned short f2bf(float f) {
    __hip_bfloat16 b = __float2bfloat16(f);   // round-to-nearest
    return *reinterpret_cast<unsigned short*>(&b);
}
static __device__ __forceinline__ float bf2f(unsigned short u) {
    unsigned int x = ((unsigned int)u) << 16;
    return __uint_as_float(x);
}

// ---------------- Kernel A: xt = x @ W (bf16 out), a_src/a_dst dots, + edge count ----------------
__global__ __launch_bounds__(256) void k_gemm(
    const float* __restrict__ x, const float* __restrict__ W,
    const float* __restrict__ att_src, const float* __restrict__ att_dst,
    unsigned short* __restrict__ xt, float* __restrict__ a_src, float* __restrict__ a_dst,
    int N, const int* __restrict__ ei, int E, int* __restrict__ deg)
{
    __shared__ float Wl[CH * CH];     // 64 KB
    __shared__ float xl[32][CH];      // 16 KB
    const int tid = threadIdx.x;

    {
        const float4* W4 = (const float4*)W;
        float4* Wl4 = (float4*)Wl;
        #pragma unroll
        for (int i = 0; i < (CH * CH / 4) / 256; ++i)
            Wl4[tid + i * 256] = W4[tid + i * 256];
    }

    const int c32 = tid & 31;
    const int rg  = tid >> 5;
    const int col = c32 * 4;
    const int h   = c32 >> 3;
    const float4 atS = ((const float4*)att_src)[c32];
    const float4 atD = ((const float4*)att_dst)[c32];

    const int r0 = blockIdx.x * 32;
    {
        const float4* x4 = (const float4*)x;
        float4* xl4 = (float4*)xl;
        #pragma unroll
        for (int i = 0; i < 4; ++i) {
            int f  = tid + i * 256;
            int rl = f >> 5, c4 = f & 31;
            int r  = r0 + rl;
            float4 v = make_float4(0.f, 0.f, 0.f, 0.f);
            if (r < N) v = x4[(size_t)r * 32 + c4];
            xl4[rl * 32 + c4] = v;
        }
    }
    __syncthreads();

    float4 acc[4];
    #pragma unroll
    for (int i = 0; i < 4; ++i) acc[i] = make_float4(0.f, 0.f, 0.f, 0.f);

    const int rbase = rg * 4;
    for (int k = 0; k < CH; k += 4) {
        float4 w0 = *(const float4*)&Wl[(k + 0) * CH + col];
        float4 w1 = *(const float4*)&Wl[(k + 1) * CH + col];
        float4 w2 = *(const float4*)&Wl[(k + 2) * CH + col];
        float4 w3 = *(const float4*)&Wl[(k + 3) * CH + col];
        #pragma unroll
        for (int rr = 0; rr < 4; ++rr) {
            float4 xv = *(const float4*)&xl[rbase + rr][k];
            acc[rr].x += xv.x * w0.x + xv.y * w1.x + xv.z * w2.x + xv.w * w3.x;
            acc[rr].y += xv.x * w0.y + xv.y * w1.y + xv.z * w2.y + xv.w * w3.y;
            acc[rr].z += xv.x * w0.z + xv.y * w1.z + xv.z * w2.z + xv.w * w3.z;
            acc[rr].w += xv.x * w0.w + xv.y * w1.w + xv.z * w2.w + xv.w * w3.w;
        }
    }

    #pragma unroll
    for (int rr = 0; rr < 4; ++rr) {
        int r = r0 + rbase + rr;
        if (r < N) {
            ushort4 uv;
            uv.x = f2bf(acc[rr].x); uv.y = f2bf(acc[rr].y);
            uv.z = f2bf(acc[rr].z); uv.w = f2bf(acc[rr].w);
            ((ushort4*)xt)[(size_t)r * 32 + c32] = uv;   // row = 128 bf16 = 32x ushort4
            float ps = acc[rr].x * atS.x + acc[rr].y * atS.y + acc[rr].z * atS.z + acc[rr].w * atS.w;
            float pd = acc[rr].x * atD.x + acc[rr].y * atD.y + acc[rr].z * atD.z + acc[rr].w * atD.w;
            #pragma unroll
            for (int m = 1; m < 8; m <<= 1) {
                ps += __shfl_xor(ps, m, 64);
                pd += __shfl_xor(pd, m, 64);
            }
            if ((c32 & 7) == 0) {
                a_src[(size_t)r * 4 + h] = ps;
                a_dst[(size_t)r * 4 + h] = pd;
            }
        }
    }

    // fused in-degree count (overlaps with other blocks' GEMM work)
    for (int i = blockIdx.x * 256 + tid; i < E; i += gridDim.x * 256)
        atomicAdd(&deg[ei[E + i]], 1);
}

// ---------------- CSR construction ----------------
// per-block exclusive scan of (deg[i]+1), 1024 elems/block of 256 threads
__global__ __launch_bounds__(256) void k_scan_block(
    const int* __restrict__ deg, int* __restrict__ off, int* __restrict__ bsum, int N)
{
    __shared__ int sdata[256];
    int base = blockIdx.x * 1024;
    int t = threadIdx.x;
    int v[4]; int s = 0;
    #pragma unroll
    for (int j = 0; j < 4; ++j) {
        int i = base + t * 4 + j;
        v[j] = (i < N) ? (deg[i] + 1) : 0;
        s += v[j];
    }
    sdata[t] = s; __syncthreads();
    for (int d = 1; d < 256; d <<= 1) {
        int x = (t >= d) ? sdata[t - d] : 0;
        __syncthreads();
        sdata[t] += x;
        __syncthreads();
    }
    int run = (t > 0) ? sdata[t - 1] : 0;
    if (t == 255) bsum[blockIdx.x] = sdata[255];
    #pragma unroll
    for (int j = 0; j < 4; ++j) {
        int i = base + t * 4 + j;
        if (i < N) off[i] = run;
        run += v[j];
    }
}

__global__ __launch_bounds__(256) void k_scan_bsum(int* __restrict__ bsum, int nb)
{
    __shared__ int sdata[256];
    int t = threadIdx.x;
    sdata[t] = (t < nb) ? bsum[t] : 0;
    __syncthreads();
    for (int d = 1; d < 256; d <<= 1) {
        int x = (t >= d) ? sdata[t - d] : 0;
        __syncthreads();
        sdata[t] += x;
        __syncthreads();
    }
    if (t < nb) bsum[t] = (t > 0) ? sdata[t - 1] : 0;
}

__global__ __launch_bounds__(256) void k_fixup(
    int* __restrict__ off, const int* __restrict__ bsum,
    int* __restrict__ cursor, int* __restrict__ csr, int N, int total)
{
    int i = blockIdx.x * 256 + threadIdx.x;
    if (i > N) return;
    if (i == N) { off[N] = total; return; }
    int o = off[i] + bsum[i >> 10];
    off[i] = o;
    cursor[i] = o + 1;   // slot o holds the self-loop
    csr[o] = i;
}

__global__ __launch_bounds__(256) void k_scatter(
    const int* __restrict__ ei, int E,
    int* __restrict__ cursor, int* __restrict__ csr)
{
    int i = blockIdx.x * 256 + threadIdx.x;
    if (i >= E) return;
    int src = ei[i], dst = ei[E + i];
    int pos = atomicAdd(&cursor[dst], 1);
    csr[pos] = src;
}

// ---------------- Kernel B: per-destination gather + normalize + relu ----------------
// one 64-lane wave per node; 4 groups of 16 lanes each own one edge; lane q
// covers cols [q*8, q*8+7] (8 bf16 = one 16B load).
__global__ __launch_bounds__(256) void k_gather(
    const int* __restrict__ off, const int* __restrict__ csr,
    const float* __restrict__ a_src, const float* __restrict__ a_dst,
    const unsigned short* __restrict__ xt, const float* __restrict__ bias,
    float* __restrict__ out, int N)
{
    int n = blockIdx.x * 4 + (threadIdx.x >> 6);
    if (n >= N) return;
    int l   = threadIdx.x & 63;
    int grp = l >> 4;   // 0..3 edge subgroup
    int q   = l & 15;   // col octet
    int h   = q >> 2;   // head

    float ad = a_dst[(size_t)n * 4 + h];
    int s = off[n], e = off[n + 1];

    float acc[8] = {0.f,0.f,0.f,0.f,0.f,0.f,0.f,0.f};
    float wsum = 0.f;
    for (int k = s + grp; k < e; k += 4) {
        int src = csr[k];
        float as = a_src[(size_t)src * 4 + h];
        float lg = as + ad;
        lg = (lg >= 0.f) ? lg : 0.2f * lg;   // LeakyReLU(0.2)
        float w = __expf(lg);                 // unnormalized; ratio identical
        wsum += w;
        float4 raw = ((const float4*)xt)[(size_t)src * 16 + q];  // 8 bf16
        union { float4 f; unsigned short u[8]; } uu; uu.f = raw;
        #pragma unroll
        for (int j = 0; j < 8; ++j) acc[j] += w * bf2f(uu.u[j]);
    }
    #pragma unroll
    for (int j = 0; j < 8; ++j) {
        acc[j] += __shfl_xor(acc[j], 16, 64);
        acc[j] += __shfl_xor(acc[j], 32, 64);
    }
    wsum += __shfl_xor(wsum, 16, 64);
    wsum += __shfl_xor(wsum, 32, 64);

    if (grp == 0) {
        float inv = 1.0f / wsum;              // >0 (self-loop)
        float4 b0 = ((const float4*)bias)[q * 2];
        float4 b1 = ((const float4*)bias)[q * 2 + 1];
        float4 v0, v1;
        v0.x = fmaxf(fmaf(acc[0], inv, b0.x), 0.f);
        v0.y = fmaxf(fmaf(acc[1], inv, b0.y), 0.f);
        v0.z = fmaxf(fmaf(acc[2], inv, b0.z), 0.f);
        v0.w = fmaxf(fmaf(acc[3], inv, b0.w), 0.f);
        v1.x = fmaxf(fmaf(acc[4], inv, b1.x), 0.f);
        v1.y = fmaxf(fmaf(acc[5], inv, b1.y), 0.f);
        v1.z = fmaxf(fmaf(acc[6], inv, b1.z), 0.f);
        v1.w = fmaxf(fmaf(acc[7], inv, b1.w), 0.f);
        ((float4*)out)[(size_t)n * 32 + q * 2]     = v0;
        ((float4*)out)[(size_t)n * 32 + q * 2 + 1] = v1;
    }
}

extern "C" void kernel_launch(void* const* d_in, const int* in_sizes, int n_in,
                              void* d_out, int out_size, void* d_ws, size_t ws_size,
                              hipStream_t stream) {
    const float* x       = (const float*)d_in[0];
    const int*   ei      = (const int*)d_in[1];
    const float* W       = (const float*)d_in[3];
    const float* att_src = (const float*)d_in[4];
    const float* att_dst = (const float*)d_in[5];
    const float* bias    = (const float*)d_in[6];

    const int N = in_sizes[0] / CH;
    const int E = in_sizes[1] / 2;
    const int total = E + N;
    float* out = (float*)d_out;

    char* ws = (char*)d_ws;
    size_t p = 0;
    unsigned short* xt = (unsigned short*)(ws + p); p += (size_t)N * CH * 2;
    float* a_src  = (float*)(ws + p); p += (size_t)N * 4 * 4;
    float* a_dst  = (float*)(ws + p); p += (size_t)N * 4 * 4;
    int*   deg    = (int*)(ws + p);   p += (size_t)N * 4;
    int*   off    = (int*)(ws + p);   p += (size_t)(N + 1) * 4;
    int*   cursor = (int*)(ws + p);   p += (size_t)N * 4;
    int*   bsum   = (int*)(ws + p);   p += 256 * 4;
    int*   csr    = (int*)(ws + p);   p += (size_t)total * 4;

    hipMemsetAsync(deg, 0, (size_t)N * 4, stream);

    k_gemm<<<(N + 31) / 32, 256, 0, stream>>>(x, W, att_src, att_dst,
                                              xt, a_src, a_dst, N, ei, E, deg);

    int nb = (N + 1023) / 1024;
    k_scan_block<<<nb, 256, 0, stream>>>(deg, off, bsum, N);
    k_scan_bsum<<<1, 256, 0, stream>>>(bsum, nb);
    k_fixup<<<(N + 256) / 256, 256, 0, stream>>>(off, bsum, cursor, csr, N, total);
    k_scatter<<<(E + 255) / 256, 256, 0, stream>>>(ei, E, cursor, csr);

    k_gather<<<(N + 3) / 4, 256, 0, stream>>>(off, csr, a_src, a_dst,
                                              xt, bias, out, N);
}

// Round 4
// 268.070 us; speedup vs baseline: 11.2725x; 1.1723x over previous
//
#include <hip/hip_runtime.h>
#include <hip/hip_bf16.h>

#define HEADS 4
#define HD 32
#define CH 128   // IN_CH == HEADS*HD == 128

static __device__ __forceinline__ unsigned short f2bf(float f) {
    __hip_bfloat16 b = __float2bfloat16(f);   // round-to-nearest
    return *reinterpret_cast<unsigned short*>(&b);
}
static __device__ __forceinline__ float bf2f(unsigned short u) {
    unsigned int x = ((unsigned int)u) << 16;
    return __uint_as_float(x);
}

// ---------------- Kernel A: xt = x @ W (bf16 out), a_src/a_dst dots, + edge count ----------------
__global__ __launch_bounds__(256) void k_gemm(
    const float* __restrict__ x, const float* __restrict__ W,
    const float* __restrict__ att_src, const float* __restrict__ att_dst,
    unsigned short* __restrict__ xt, float* __restrict__ a_src, float* __restrict__ a_dst,
    int N, const int* __restrict__ ei, int E, int* __restrict__ deg)
{
    __shared__ float Wl[CH * CH];     // 64 KB
    __shared__ float xl[32][CH];      // 16 KB
    const int tid = threadIdx.x;

    {
        const float4* W4 = (const float4*)W;
        float4* Wl4 = (float4*)Wl;
        #pragma unroll
        for (int i = 0; i < (CH * CH / 4) / 256; ++i)
            Wl4[tid + i * 256] = W4[tid + i * 256];
    }

    const int c32 = tid & 31;
    const int rg  = tid >> 5;
    const int col = c32 * 4;
    const int h   = c32 >> 3;
    const float4 atS = ((const float4*)att_src)[c32];
    const float4 atD = ((const float4*)att_dst)[c32];

    const int r0 = blockIdx.x * 32;
    {
        const float4* x4 = (const float4*)x;
        float4* xl4 = (float4*)xl;
        #pragma unroll
        for (int i = 0; i < 4; ++i) {
            int f  = tid + i * 256;
            int rl = f >> 5, c4 = f & 31;
            int r  = r0 + rl;
            float4 v = make_float4(0.f, 0.f, 0.f, 0.f);
            if (r < N) v = x4[(size_t)r * 32 + c4];
            xl4[rl * 32 + c4] = v;
        }
    }
    __syncthreads();

    float4 acc[4];
    #pragma unroll
    for (int i = 0; i < 4; ++i) acc[i] = make_float4(0.f, 0.f, 0.f, 0.f);

    const int rbase = rg * 4;
    for (int k = 0; k < CH; k += 4) {
        float4 w0 = *(const float4*)&Wl[(k + 0) * CH + col];
        float4 w1 = *(const float4*)&Wl[(k + 1) * CH + col];
        float4 w2 = *(const float4*)&Wl[(k + 2) * CH + col];
        float4 w3 = *(const float4*)&Wl[(k + 3) * CH + col];
        #pragma unroll
        for (int rr = 0; rr < 4; ++rr) {
            float4 xv = *(const float4*)&xl[rbase + rr][k];
            acc[rr].x += xv.x * w0.x + xv.y * w1.x + xv.z * w2.x + xv.w * w3.x;
            acc[rr].y += xv.x * w0.y + xv.y * w1.y + xv.z * w2.y + xv.w * w3.y;
            acc[rr].z += xv.x * w0.z + xv.y * w1.z + xv.z * w2.z + xv.w * w3.z;
            acc[rr].w += xv.x * w0.w + xv.y * w1.w + xv.z * w2.w + xv.w * w3.w;
        }
    }

    #pragma unroll
    for (int rr = 0; rr < 4; ++rr) {
        int r = r0 + rbase + rr;
        if (r < N) {
            ushort4 uv;
            uv.x = f2bf(acc[rr].x); uv.y = f2bf(acc[rr].y);
            uv.z = f2bf(acc[rr].z); uv.w = f2bf(acc[rr].w);
            ((ushort4*)xt)[(size_t)r * 32 + c32] = uv;   // row = 128 bf16
            float ps = acc[rr].x * atS.x + acc[rr].y * atS.y + acc[rr].z * atS.z + acc[rr].w * atS.w;
            float pd = acc[rr].x * atD.x + acc[rr].y * atD.y + acc[rr].z * atD.z + acc[rr].w * atD.w;
            #pragma unroll
            for (int m = 1; m < 8; m <<= 1) {
                ps += __shfl_xor(ps, m, 64);
                pd += __shfl_xor(pd, m, 64);
            }
            if ((c32 & 7) == 0) {
                a_src[(size_t)r * 4 + h] = ps;
                a_dst[(size_t)r * 4 + h] = pd;
            }
        }
    }

    // fused in-degree count (overlaps with other blocks' GEMM work)
    for (int i = blockIdx.x * 256 + tid; i < E; i += gridDim.x * 256)
        atomicAdd(&deg[ei[E + i]], 1);
}

// ---------------- CSR construction ----------------
__global__ __launch_bounds__(256) void k_scan_block(
    const int* __restrict__ deg, int* __restrict__ off, int* __restrict__ bsum, int N)
{
    __shared__ int sdata[256];
    int base = blockIdx.x * 1024;
    int t = threadIdx.x;
    int v[4]; int s = 0;
    #pragma unroll
    for (int j = 0; j < 4; ++j) {
        int i = base + t * 4 + j;
        v[j] = (i < N) ? (deg[i] + 1) : 0;
        s += v[j];
    }
    sdata[t] = s; __syncthreads();
    for (int d = 1; d < 256; d <<= 1) {
        int x = (t >= d) ? sdata[t - d] : 0;
        __syncthreads();
        sdata[t] += x;
        __syncthreads();
    }
    int run = (t > 0) ? sdata[t - 1] : 0;
    if (t == 255) bsum[blockIdx.x] = sdata[255];
    #pragma unroll
    for (int j = 0; j < 4; ++j) {
        int i = base + t * 4 + j;
        if (i < N) off[i] = run;
        run += v[j];
    }
}

__global__ __launch_bounds__(256) void k_scan_bsum(int* __restrict__ bsum, int nb)
{
    __shared__ int sdata[256];
    int t = threadIdx.x;
    sdata[t] = (t < nb) ? bsum[t] : 0;
    __syncthreads();
    for (int d = 1; d < 256; d <<= 1) {
        int x = (t >= d) ? sdata[t - d] : 0;
        __syncthreads();
        sdata[t] += x;
        __syncthreads();
    }
    if (t < nb) bsum[t] = (t > 0) ? sdata[t - 1] : 0;
}

__global__ __launch_bounds__(256) void k_fixup(
    int* __restrict__ off, const int* __restrict__ bsum,
    int* __restrict__ cursor, int* __restrict__ csr, int N, int total)
{
    int i = blockIdx.x * 256 + threadIdx.x;
    if (i > N) return;
    if (i == N) { off[N] = total; return; }
    int o = off[i] + bsum[i >> 10];
    off[i] = o;
    cursor[i] = o + 1;   // slot o holds the self-loop
    csr[o] = i;
}

// XCD-sliced scatter: 8 cohorts (slice = blockIdx&7, round-robin -> one XCD each).
// Each cohort scans ALL edges, scatters only dst in its node slice -> cursor/csr
// writes stay XCD-L2-local, written back once. Coverage exact regardless of the
// real block->XCD mapping (locality heuristic only).
__global__ __launch_bounds__(256) void k_scatter(
    const int* __restrict__ ei, int E, int N,
    int* __restrict__ cursor, int* __restrict__ csr)
{
    int slice = blockIdx.x & 7;
    int c     = blockIdx.x >> 3;
    int B     = gridDim.x >> 3;
    int lo = (int)((long long)N * slice / 8);
    int hi = (int)((long long)N * (slice + 1) / 8);

    for (int i = c * 256 + threadIdx.x; i < E; i += B * 256) {
        int dst = ei[E + i];
        if (dst >= lo && dst < hi) {
            int src = ei[i];
            int pos = atomicAdd(&cursor[dst], 1);
            csr[pos] = src;
        }
    }
}

// ---------------- Kernel B: per-destination gather + normalize + relu ----------------
__global__ __launch_bounds__(256) void k_gather(
    const int* __restrict__ off, const int* __restrict__ csr,
    const float* __restrict__ a_src, const float* __restrict__ a_dst,
    const unsigned short* __restrict__ xt, const float* __restrict__ bias,
    float* __restrict__ out, int N)
{
    int n = blockIdx.x * 4 + (threadIdx.x >> 6);
    if (n >= N) return;
    int l   = threadIdx.x & 63;
    int grp = l >> 4;   // 0..3 edge subgroup
    int q   = l & 15;   // col octet
    int h   = q >> 2;   // head

    float ad = a_dst[(size_t)n * 4 + h];
    int s = off[n], e = off[n + 1];

    float acc[8] = {0.f,0.f,0.f,0.f,0.f,0.f,0.f,0.f};
    float wsum = 0.f;
    for (int k = s + grp; k < e; k += 4) {
        int src = csr[k];
        float as = a_src[(size_t)src * 4 + h];
        float lg = as + ad;
        lg = (lg >= 0.f) ? lg : 0.2f * lg;   // LeakyReLU(0.2)
        float w = __expf(lg);                 // unnormalized; ratio identical
        wsum += w;
        float4 raw = ((const float4*)xt)[(size_t)src * 16 + q];  // 8 bf16
        union { float4 f; unsigned short u[8]; } uu; uu.f = raw;
        #pragma unroll
        for (int j = 0; j < 8; ++j) acc[j] += w * bf2f(uu.u[j]);
    }
    #pragma unroll
    for (int j = 0; j < 8; ++j) {
        acc[j] += __shfl_xor(acc[j], 16, 64);
        acc[j] += __shfl_xor(acc[j], 32, 64);
    }
    wsum += __shfl_xor(wsum, 16, 64);
    wsum += __shfl_xor(wsum, 32, 64);

    if (grp == 0) {
        float inv = 1.0f / wsum;              // >0 (self-loop)
        float4 b0 = ((const float4*)bias)[q * 2];
        float4 b1 = ((const float4*)bias)[q * 2 + 1];
        float4 v0, v1;
        v0.x = fmaxf(fmaf(acc[0], inv, b0.x), 0.f);
        v0.y = fmaxf(fmaf(acc[1], inv, b0.y), 0.f);
        v0.z = fmaxf(fmaf(acc[2], inv, b0.z), 0.f);
        v0.w = fmaxf(fmaf(acc[3], inv, b0.w), 0.f);
        v1.x = fmaxf(fmaf(acc[4], inv, b1.x), 0.f);
        v1.y = fmaxf(fmaf(acc[5], inv, b1.y), 0.f);
        v1.z = fmaxf(fmaf(acc[6], inv, b1.z), 0.f);
        v1.w = fmaxf(fmaf(acc[7], inv, b1.w), 0.f);
        ((float4*)out)[(size_t)n * 32 + q * 2]     = v0;
        ((float4*)out)[(size_t)n * 32 + q * 2 + 1] = v1;
    }
}

extern "C" void kernel_launch(void* const* d_in, const int* in_sizes, int n_in,
                              void* d_out, int out_size, void* d_ws, size_t ws_size,
                              hipStream_t stream) {
    const float* x       = (const float*)d_in[0];
    const int*   ei      = (const int*)d_in[1];
    const float* W       = (const float*)d_in[3];
    const float* att_src = (const float*)d_in[4];
    const float* att_dst = (const float*)d_in[5];
    const float* bias    = (const float*)d_in[6];

    const int N = in_sizes[0] / CH;
    const int E = in_sizes[1] / 2;
    const int total = E + N;
    float* out = (float*)d_out;

    char* ws = (char*)d_ws;
    size_t p = 0;
    unsigned short* xt = (unsigned short*)(ws + p); p += (size_t)N * CH * 2;
    float* a_src  = (float*)(ws + p); p += (size_t)N * 4 * 4;
    float* a_dst  = (float*)(ws + p); p += (size_t)N * 4 * 4;
    int*   deg    = (int*)(ws + p);   p += (size_t)N * 4;
    int*   off    = (int*)(ws + p);   p += (size_t)(N + 1) * 4;
    int*   cursor = (int*)(ws + p);   p += (size_t)N * 4;
    int*   bsum   = (int*)(ws + p);   p += 256 * 4;
    int*   csr    = (int*)(ws + p);   p += (size_t)total * 4;

    hipMemsetAsync(deg, 0, (size_t)N * 4, stream);

    k_gemm<<<(N + 31) / 32, 256, 0, stream>>>(x, W, att_src, att_dst,
                                              xt, a_src, a_dst, N, ei, E, deg);

    int nb = (N + 1023) / 1024;
    k_scan_block<<<nb, 256, 0, stream>>>(deg, off, bsum, N);
    k_scan_bsum<<<1, 256, 0, stream>>>(bsum, nb);
    k_fixup<<<(N + 256) / 256, 256, 0, stream>>>(off, bsum, cursor, csr, N, total);

    k_scatter<<<2048, 256, 0, stream>>>(ei, E, N, cursor, csr);

    k_gather<<<(N + 3) / 4, 256, 0, stream>>>(off, csr, a_src, a_dst,
                                              xt, bias, out, N);
}